// Round 2
// baseline (739.831 us; speedup 1.0000x reference)
//
#include <hip/hip_runtime.h>
#include <hip/hip_bf16.h>

// Problem constants
#define Bz 8
#define Tn 64
#define Mn 500
#define KC 16
#define HA 64
#define HR 64
#define NHID 32
#define DF 160
#define FINALC 512

typedef float in_t;   // reference dtypes are all float32

__device__ __forceinline__ float b2f(in_t v){ return v; }
__device__ __forceinline__ float sigm(float x){ return 1.0f/(1.0f+__expf(-x)); }
__device__ __forceinline__ float tanhfast(float x){ float e=__expf(2.0f*x); return 1.0f-2.0f/(e+1.0f); }
__device__ __forceinline__ float eluf(float x){ return x>0.0f? x : (__expf(x)-1.0f); }

// ---------------------------------------------------------------------------
// K1: per-node convs -> h_SC (relu), also writes feats0[0:32]
// short conv: kernel covers full T (output len 1).
// long conv (dilation 2, len 32): output len 2, mean folds to coeff 0.5*wl[t>>1].
__global__ __launch_bounds__(128) void k_conv(
    const in_t* __restrict__ x, const in_t* __restrict__ wsw, const in_t* __restrict__ wsb,
    const in_t* __restrict__ wlw, const in_t* __restrict__ wlb,
    float* __restrict__ hSC, float* __restrict__ f0)
{
  __shared__ float sw[KC*Tn];
  __shared__ float lw[KC*Tn];
  __shared__ float sb[KC], lb[KC];
  int tid = threadIdx.x;
  for (int idx = tid; idx < KC*Tn; idx += blockDim.x) {
    sw[idx] = b2f(wsw[idx]);
    int k = idx >> 6, t = idx & 63;
    lw[idx] = 0.5f * b2f(wlw[k*32 + (t>>1)]);
  }
  if (tid < KC) { sb[tid] = b2f(wsb[tid]); lb[tid] = b2f(wlb[tid]); }
  __syncthreads();
  int m = blockIdx.x * blockDim.x + tid;
  int b = blockIdx.y;
  if (m >= Mn) return;
  float xv[Tn];
  const in_t* xp = x + (size_t)b*Tn*Mn + m;
  #pragma unroll
  for (int t = 0; t < Tn; ++t) xv[t] = b2f(xp[t*Mn]);
  float* hp = hSC + ((size_t)b*Mn + m) * (2*KC);
  float* fp = f0  + ((size_t)b*Mn + m) * DF;
  for (int k = 0; k < KC; ++k) {
    float s = 0.f, l = 0.f;
    #pragma unroll
    for (int t = 0; t < Tn; ++t) { s += xv[t]*sw[k*Tn+t]; l += xv[t]*lw[k*Tn+t]; }
    float vs = fmaxf(s + sb[k], 0.f);
    float vl = fmaxf(l + lb[k], 0.f);
    hp[k] = vs; hp[KC+k] = vl;
    fp[k] = vs; fp[KC+k] = vl;
  }
}

// ---------------------------------------------------------------------------
// K2: Q/K projections (hidA=64 each from 32 features)
__global__ __launch_bounds__(256) void k_qk(
    const float* __restrict__ hSC, const in_t* __restrict__ WQw, const in_t* __restrict__ WQb,
    const in_t* __restrict__ WKw, const in_t* __restrict__ WKb,
    float* __restrict__ Q, float* __restrict__ Kt)
{
  __shared__ float wq[HA*32], wk[HA*32], bq[HA], bk[HA];
  int tid = threadIdx.x;
  for (int i = tid; i < HA*32; i += 256) { wq[i] = b2f(WQw[i]); wk[i] = b2f(WKw[i]); }
  for (int i = tid; i < HA; i += 256) { bq[i] = b2f(WQb[i]); bk[i] = b2f(WKb[i]); }
  __syncthreads();
  int gid = blockIdx.x*256 + tid;
  if (gid >= Bz*Mn) return;
  float h[32];
  const float* hp = hSC + (size_t)gid*32;
  #pragma unroll
  for (int c = 0; c < 32; ++c) h[c] = hp[c];
  float* qp = Q + (size_t)gid*HA;
  float* kp = Kt + (size_t)gid*HA;
  for (int a = 0; a < HA; ++a) {
    float aq = bq[a], ak = bk[a];
    #pragma unroll
    for (int c = 0; c < 32; ++c) { aq += h[c]*wq[a*32+c]; ak += h[c]*wk[a*32+c]; }
    qp[a] = aq; kp[a] = ak;
  }
}

// ---------------------------------------------------------------------------
// K3: per-batch Ksum[64] and Gram G = sum_m K_m K_m^T  (64x64)
__global__ __launch_bounds__(256) void k_gram(
    const float* __restrict__ Kt, float* __restrict__ G, float* __restrict__ Ksum)
{
  int b = blockIdx.x; int tid = threadIdx.x;
  __shared__ float L[64][HA];
  int p = tid & 63;
  int q0 = (tid >> 6) * 16;
  float acc[16];
  #pragma unroll
  for (int e = 0; e < 16; ++e) acc[e] = 0.f;
  float ks = 0.f;
  for (int m0 = 0; m0 < Mn; m0 += 64) {
    __syncthreads();
    for (int idx = tid; idx < 64*HA; idx += 256) {
      int r = idx >> 6, c = idx & 63;
      int m = m0 + r;
      L[r][c] = (m < Mn) ? Kt[((size_t)b*Mn + m)*HA + c] : 0.f;
    }
    __syncthreads();
    #pragma unroll 4
    for (int r = 0; r < 64; ++r) {
      float lp = L[r][p];
      if (tid < 64) ks += lp;
      #pragma unroll
      for (int e = 0; e < 16; ++e) acc[e] += lp * L[r][q0+e];
    }
  }
  if (tid < 64) Ksum[b*HA + tid] = ks;
  float* gp = G + (size_t)b*HA*HA;
  #pragma unroll
  for (int e = 0; e < 16; ++e) gp[p*HA + q0 + e] = acc[e];
}

// ---------------------------------------------------------------------------
// K4: s = (Q_i . Ksum) / max(sqrt(Q_i^T G Q_i),1e-12); write feats0[32:160]
__global__ __launch_bounds__(256) void k_sglob(
    const float* __restrict__ Q, const float* __restrict__ G, const float* __restrict__ Ksum,
    const in_t* __restrict__ degree, const in_t* __restrict__ tencw, const in_t* __restrict__ tencb,
    const in_t* __restrict__ sencw, const in_t* __restrict__ sencb, float* __restrict__ f0)
{
  int b = blockIdx.y;
  __shared__ float Gs[HA*HA];
  __shared__ float Ks[HA], tw[HR], tb[HR], sw2[HR], sb2[HR];
  int tid = threadIdx.x;
  for (int i = tid; i < HA*HA; i += 256) Gs[i] = G[(size_t)b*HA*HA + i];
  for (int i = tid; i < HA; i += 256) {
    Ks[i] = Ksum[b*HA + i];
    tw[i] = b2f(tencw[i]); tb[i] = b2f(tencb[i]);
    sw2[i] = b2f(sencw[i]); sb2[i] = b2f(sencb[i]);
  }
  __syncthreads();
  int m = blockIdx.x*256 + tid;
  if (m >= Mn) return;
  const float* qp = Q + ((size_t)b*Mn + m)*HA;
  float q[HA];
  #pragma unroll
  for (int i = 0; i < HA; ++i) q[i] = qp[i];
  float rs = 0.f, qq = 0.f;
  for (int p = 0; p < HA; ++p) {
    float t = 0.f;
    #pragma unroll
    for (int c = 0; c < HA; ++c) t += Gs[p*HA + c] * q[c];
    float qpv = qp[p];           // reload (cached) to avoid dynamic reg indexing
    qq += qpv * t;
    rs += qpv * Ks[p];
  }
  float nrm = fmaxf(sqrtf(fmaxf(qq, 0.f)), 1e-12f);
  float s = rs / nrm;
  float dg = b2f(degree[m]);
  float* fp = f0 + ((size_t)b*Mn + m)*DF;
  for (int r = 0; r < HR; ++r) {
    fp[32 + r] = s*tw[r] + tb[r];
    fp[96 + r] = dg*sw2[r] + sb2[r];
  }
}

// ---------------------------------------------------------------------------
// K5: GRU (input size 1, NH=32, T=64). 32 lanes per sequence, 8 seq/block.
__global__ __launch_bounds__(256) void k_gru(
    const in_t* __restrict__ x, const in_t* __restrict__ Wih, const in_t* __restrict__ Whh,
    const in_t* __restrict__ bih, const in_t* __restrict__ bhh, float* __restrict__ lh)
{
  int tid = threadIdx.x;
  int lane = tid & 31;
  int seq = blockIdx.x*8 + (tid >> 5);         // 0..3999 (500 blocks * 8 exact)
  int b = seq / Mn, m = seq - b*Mn;
  float wr[32], wz[32], wn[32];
  #pragma unroll
  for (int j = 0; j < 32; ++j) {
    wr[j] = b2f(Whh[(0*32 + lane)*32 + j]);
    wz[j] = b2f(Whh[(32 + lane)*32 + j]);
    wn[j] = b2f(Whh[(64 + lane)*32 + j]);
  }
  float wir = b2f(Wih[lane]),   wiz = b2f(Wih[32+lane]),   win = b2f(Wih[64+lane]);
  float bir = b2f(bih[lane]),   biz = b2f(bih[32+lane]),   bin_ = b2f(bih[64+lane]);
  float bhr = b2f(bhh[lane]),   bhz = b2f(bhh[32+lane]),   bhn = b2f(bhh[64+lane]);
  float h = 0.f;
  const in_t* xp = x + (size_t)b*Tn*Mn + m;
  for (int t = 0; t < Tn; ++t) {
    float xt = b2f(xp[t*Mn]);
    float gr = bhr, gz = bhz, gn = bhn;
    #pragma unroll
    for (int j = 0; j < 32; ++j) {
      float hj = __shfl(h, j, 32);
      gr += wr[j]*hj; gz += wz[j]*hj; gn += wn[j]*hj;
    }
    float r = sigm(xt*wir + bir + gr);
    float z = sigm(xt*wiz + biz + gz);
    float n = tanhfast(xt*win + bin_ + r*gn);
    h = (1.f - z)*n + z*h;
  }
  lh[(size_t)seq*NHID + lane] = h;
}

// ---------------------------------------------------------------------------
// K6: A1 = lh@W1^T, A2 = lh@W2^T
__global__ __launch_bounds__(256) void k_a1a2(
    const float* __restrict__ lh, const in_t* __restrict__ W1, const in_t* __restrict__ W2,
    float* __restrict__ A1, float* __restrict__ A2)
{
  __shared__ float w1[32*32], w2[32*32];
  int tid = threadIdx.x;
  for (int i = tid; i < 1024; i += 256) { w1[i] = b2f(W1[i]); w2[i] = b2f(W2[i]); }
  __syncthreads();
  int gid = blockIdx.x*256 + tid;
  if (gid >= Bz*Mn) return;
  float h[32];
  #pragma unroll
  for (int c = 0; c < 32; ++c) h[c] = lh[(size_t)gid*32 + c];
  float* a1 = A1 + (size_t)gid*32;
  float* a2 = A2 + (size_t)gid*32;
  for (int a = 0; a < 32; ++a) {
    float s1 = 0.f, s2 = 0.f;
    #pragma unroll
    for (int c = 0; c < 32; ++c) { s1 += h[c]*w1[a*32+c]; s2 += h[c]*w2[a*32+c]; }
    a1[a] = s1; a2[a] = s2;
  }
}

// ---------------------------------------------------------------------------
// K7: dmat[i,j] = sigmoid(d_gate[i,j]*deg_i*deg_j)   (batch independent)
__global__ __launch_bounds__(256) void k_dmat(
    const in_t* __restrict__ dgate, const in_t* __restrict__ degree, float* __restrict__ dmat)
{
  int idx = blockIdx.x*256 + threadIdx.x;
  if (idx >= Mn*Mn) return;
  int i = idx / Mn, j = idx - i*Mn;
  dmat[idx] = sigm(b2f(dgate[idx]) * b2f(degree[i]) * b2f(degree[j]));
}

// ---------------------------------------------------------------------------
// K8: a[b,i,j] = V . elu(A1_i + A2_j + b1) + bv
__global__ __launch_bounds__(256) void k_pair(
    const float* __restrict__ A1, const float* __restrict__ A2, const in_t* __restrict__ Vv,
    const in_t* __restrict__ b1, const in_t* __restrict__ bv, float* __restrict__ aB)
{
  __shared__ float a1s[16][33], a2s[16][33], vs[32], b1s[32];
  int b = blockIdx.z;
  int i0 = blockIdx.y*16, j0 = blockIdx.x*16;
  int tid = threadIdx.x;
  if (tid < 32) { vs[tid] = b2f(Vv[tid]); b1s[tid] = b2f(b1[tid]); }
  {
    int r = tid >> 5, c = tid & 31;
    for (int rr = r; rr < 16; rr += 8) {
      int i = i0 + rr, j = j0 + rr;
      a1s[rr][c] = (i < Mn) ? A1[((size_t)b*Mn + i)*32 + c] : 0.f;
      a2s[rr][c] = (j < Mn) ? A2[((size_t)b*Mn + j)*32 + c] : 0.f;
    }
  }
  __syncthreads();
  int ti = tid >> 4, tj = tid & 15;
  int i = i0 + ti, j = j0 + tj;
  if (i >= Mn || j >= Mn) return;
  float acc = 0.f;
  #pragma unroll
  for (int c = 0; c < 32; ++c) {
    float u = a1s[ti][c] + a2s[tj][c] + b1s[c];
    acc += eluf(u) * vs[c];
  }
  aB[((size_t)b*Mn + i)*Mn + j] = acc + b2f(bv[0]);
}

// ---------------------------------------------------------------------------
// K9: column inverse norms of a (l2norm over axis=1, i.e. over i)
__global__ __launch_bounds__(128) void k_cnorm(const float* __restrict__ aB, float* __restrict__ cinv)
{
  int b = blockIdx.y;
  int j = blockIdx.x*128 + threadIdx.x;
  if (j >= Mn) return;
  const float* ap = aB + (size_t)b*Mn*Mn + j;
  float ss = 0.f;
  for (int i = 0; i < Mn; ++i) { float v = ap[(size_t)i*Mn]; ss += v*v; }
  cinv[b*Mn + j] = 1.f / fmaxf(sqrtf(ss), 1e-12f);
}

// ---------------------------------------------------------------------------
// K10: c_gate GEMM (an @ Wb) + fused adj epilogue -> adj_bin
__global__ __launch_bounds__(256) void k_cgemm(
    const float* __restrict__ aB, const float* __restrict__ cinv, const in_t* __restrict__ Wb,
    const in_t* __restrict__ wb, const in_t* __restrict__ adj_geo, const float* __restrict__ dmat,
    float* __restrict__ adjb)
{
  int b = blockIdx.z;
  int i0 = blockIdx.y*64, j0 = blockIdx.x*64;
  __shared__ float As[64][17], Bs[16][65];
  int tid = threadIdx.x;
  int ty = tid >> 4, tx = tid & 15;
  float acc[4][4] = {};
  const float* aRow = aB + (size_t)b*Mn*Mn;
  const float* civ = cinv + b*Mn;
  for (int k0 = 0; k0 < Mn; k0 += 16) {
    for (int idx = tid; idx < 64*16; idx += 256) {
      int r = idx >> 4, c = idx & 15;
      int i = i0 + r, k = k0 + c;
      As[r][c] = (i < Mn && k < Mn) ? aRow[(size_t)i*Mn + k] * civ[k] : 0.f;
    }
    for (int idx = tid; idx < 16*64; idx += 256) {
      int r = idx >> 6, c = idx & 63;
      int k = k0 + r, j = j0 + c;
      Bs[r][c] = (k < Mn && j < Mn) ? b2f(Wb[(size_t)k*Mn + j]) : 0.f;
    }
    __syncthreads();
    #pragma unroll
    for (int kk = 0; kk < 16; ++kk) {
      float ra[4], rb[4];
      #pragma unroll
      for (int e = 0; e < 4; ++e) { ra[e] = As[ty*4+e][kk]; rb[e] = Bs[kk][tx*4+e]; }
      #pragma unroll
      for (int p = 0; p < 4; ++p)
        #pragma unroll
        for (int q = 0; q < 4; ++q) acc[p][q] += ra[p]*rb[q];
    }
    __syncthreads();
  }
  float wbv = b2f(wb[0]);
  #pragma unroll
  for (int p = 0; p < 4; ++p) {
    int i = i0 + ty*4 + p;
    if (i >= Mn) continue;
    #pragma unroll
    for (int q = 0; q < 4; ++q) {
      int j = j0 + tx*4 + q;
      if (j >= Mn) continue;
      float cg = sigm(acc[p][q] + wbv);
      float av = aRow[(size_t)i*Mn + j] * civ[j];
      float ag = b2f(adj_geo[(size_t)i*Mn + j]);
      float adjf = ag*cg + av*(1.f - cg) + dmat[(size_t)i*Mn + j]*ag;
      adjb[((size_t)b*Mn + i)*Mn + j] = (adjf > 0.f) ? 1.f : adjf;
    }
  }
}

// ---------------------------------------------------------------------------
// K11: laplace = row-normalize adj_bin in place (D^-1 A with deg>0 guard)
__global__ __launch_bounds__(256) void k_lap(float* __restrict__ adjb)
{
  int b = blockIdx.y, i = blockIdx.x;
  float* row = adjb + ((size_t)b*Mn + i)*Mn;
  int tid = threadIdx.x;
  float s = 0.f;
  for (int j = tid; j < Mn; j += 256) s += row[j];
  __shared__ float red[8];
  int lane = tid & 63, wv = tid >> 6;
  #pragma unroll
  for (int off = 32; off; off >>= 1) s += __shfl_down(s, off);
  if (lane == 0) red[wv] = s;
  __syncthreads();
  if (tid == 0) {
    float d = red[0] + red[1] + red[2] + red[3];
    red[4] = (d > 0.f) ? 1.f/d : 0.f;
  }
  __syncthreads();
  float inv = red[4];
  for (int j = tid; j < Mn; j += 256) row[j] *= inv;
}

// ---------------------------------------------------------------------------
// K12: spmm tmp = laplace @ feats  ([500,500] @ [500,160] per batch)
__global__ __launch_bounds__(256) void k_spmm(
    const float* __restrict__ lap, const float* __restrict__ fin, float* __restrict__ outp)
{
  int b = blockIdx.z;
  int i0 = blockIdx.y*64, j0 = blockIdx.x*64;
  __shared__ float As[64][17], Bs[16][65];
  int tid = threadIdx.x;
  int ty = tid >> 4, tx = tid & 15;
  float acc[4][4] = {};
  const float* A = lap + (size_t)b*Mn*Mn;
  const float* Bm = fin + (size_t)b*Mn*DF;
  for (int k0 = 0; k0 < Mn; k0 += 16) {
    for (int idx = tid; idx < 64*16; idx += 256) {
      int r = idx >> 4, c = idx & 15;
      int i = i0 + r, k = k0 + c;
      As[r][c] = (i < Mn && k < Mn) ? A[(size_t)i*Mn + k] : 0.f;
    }
    for (int idx = tid; idx < 16*64; idx += 256) {
      int r = idx >> 6, c = idx & 63;
      int k = k0 + r, j = j0 + c;
      Bs[r][c] = (k < Mn && j < DF) ? Bm[(size_t)k*DF + j] : 0.f;
    }
    __syncthreads();
    #pragma unroll
    for (int kk = 0; kk < 16; ++kk) {
      float ra[4], rb[4];
      #pragma unroll
      for (int e = 0; e < 4; ++e) { ra[e] = As[ty*4+e][kk]; rb[e] = Bs[kk][tx*4+e]; }
      #pragma unroll
      for (int p = 0; p < 4; ++p)
        #pragma unroll
        for (int q = 0; q < 4; ++q) acc[p][q] += ra[p]*rb[q];
    }
    __syncthreads();
  }
  float* Om = outp + (size_t)b*Mn*DF;
  #pragma unroll
  for (int p = 0; p < 4; ++p) {
    int i = i0 + ty*4 + p;
    if (i >= Mn) continue;
    #pragma unroll
    for (int q = 0; q < 4; ++q) {
      int j = j0 + tx*4 + q;
      if (j < DF) Om[(size_t)i*DF + j] = acc[p][q];
    }
  }
}

// ---------------------------------------------------------------------------
// K13: dense feats_out = elu(tin @ W + bias)   ([4000,160] @ [160,160])
__global__ __launch_bounds__(256) void k_dense(
    const float* __restrict__ tin, const in_t* __restrict__ W, const in_t* __restrict__ bias,
    float* __restrict__ fout)
{
  int i0 = blockIdx.y*64, j0 = blockIdx.x*64;
  __shared__ float As[64][17], Bs[16][65];
  int tid = threadIdx.x;
  int ty = tid >> 4, tx = tid & 15;
  float acc[4][4] = {};
  const int NR = Bz*Mn;
  for (int k0 = 0; k0 < DF; k0 += 16) {
    for (int idx = tid; idx < 64*16; idx += 256) {
      int r = idx >> 4, c = idx & 15;
      int i = i0 + r, k = k0 + c;
      As[r][c] = (i < NR) ? tin[(size_t)i*DF + k] : 0.f;
    }
    for (int idx = tid; idx < 16*64; idx += 256) {
      int r = idx >> 6, c = idx & 63;
      int k = k0 + r, j = j0 + c;
      Bs[r][c] = (j < DF) ? b2f(W[(size_t)k*DF + j]) : 0.f;
    }
    __syncthreads();
    #pragma unroll
    for (int kk = 0; kk < 16; ++kk) {
      float ra[4], rb[4];
      #pragma unroll
      for (int e = 0; e < 4; ++e) { ra[e] = As[ty*4+e][kk]; rb[e] = Bs[kk][tx*4+e]; }
      #pragma unroll
      for (int p = 0; p < 4; ++p)
        #pragma unroll
        for (int q = 0; q < 4; ++q) acc[p][q] += ra[p]*rb[q];
    }
    __syncthreads();
  }
  #pragma unroll
  for (int p = 0; p < 4; ++p) {
    int i = i0 + ty*4 + p;
    if (i >= NR) continue;
    #pragma unroll
    for (int q = 0; q < 4; ++q) {
      int j = j0 + tx*4 + q;
      if (j < DF) fout[(size_t)i*DF + j] = eluf(acc[p][q] + b2f(bias[j]));
    }
  }
}

// ---------------------------------------------------------------------------
// K14: output projection over concat([f0,f1,f2,lh]) (512 channels)
__global__ __launch_bounds__(256) void k_out(
    const float* __restrict__ f0, const float* __restrict__ f1, const float* __restrict__ f2,
    const float* __restrict__ lh, const in_t* __restrict__ ow, const in_t* __restrict__ ob,
    float* __restrict__ outp)
{
  __shared__ float w[FINALC];
  int tid = threadIdx.x;
  for (int i = tid; i < FINALC; i += 256) w[i] = b2f(ow[i]);
  __syncthreads();
  int gid = blockIdx.x*256 + tid;
  if (gid >= Bz*Mn) return;
  float s = b2f(ob[0]);
  const float* p0 = f0 + (size_t)gid*DF;
  const float* p1 = f1 + (size_t)gid*DF;
  const float* p2 = f2 + (size_t)gid*DF;
  const float* pl = lh + (size_t)gid*NHID;
  for (int c = 0; c < DF; ++c) s += p0[c]*w[c];
  for (int c = 0; c < DF; ++c) s += p1[c]*w[DF + c];
  for (int c = 0; c < DF; ++c) s += p2[c]*w[2*DF + c];
  for (int c = 0; c < NHID; ++c) s += pl[c]*w[3*DF + c];
  outp[gid] = s;
}

// ---------------------------------------------------------------------------
extern "C" void kernel_launch(void* const* d_in, const int* in_sizes, int n_in,
                              void* d_out, int out_size, void* d_ws, size_t ws_size,
                              hipStream_t stream)
{
  const in_t* x       = (const in_t*)d_in[0];
  const in_t* adj_geo = (const in_t*)d_in[1];
  const in_t* degree  = (const in_t*)d_in[2];
  const in_t* conv_s_w= (const in_t*)d_in[3];
  const in_t* conv_s_b= (const in_t*)d_in[4];
  const in_t* conv_l_w= (const in_t*)d_in[5];
  const in_t* conv_l_b= (const in_t*)d_in[6];
  const in_t* WQ_w    = (const in_t*)d_in[7];
  const in_t* WQ_b    = (const in_t*)d_in[8];
  const in_t* WK_w    = (const in_t*)d_in[9];
  const in_t* WK_b    = (const in_t*)d_in[10];
  const in_t* tenc_w  = (const in_t*)d_in[11];
  const in_t* tenc_b  = (const in_t*)d_in[12];
  const in_t* senc_w  = (const in_t*)d_in[13];
  const in_t* senc_b  = (const in_t*)d_in[14];
  const in_t* gru_Wih = (const in_t*)d_in[15];
  const in_t* gru_Whh = (const in_t*)d_in[16];
  const in_t* gru_bih = (const in_t*)d_in[17];
  const in_t* gru_bhh = (const in_t*)d_in[18];
  const in_t* Vv      = (const in_t*)d_in[19];
  const in_t* W1      = (const in_t*)d_in[20];
  const in_t* W2      = (const in_t*)d_in[21];
  const in_t* Wb      = (const in_t*)d_in[22];
  const in_t* bv      = (const in_t*)d_in[23];
  const in_t* b1      = (const in_t*)d_in[24];
  const in_t* wb      = (const in_t*)d_in[25];
  const in_t* d_gate  = (const in_t*)d_in[26];
  const in_t* gnn_w   = (const in_t*)d_in[27];
  const in_t* gnn_b   = (const in_t*)d_in[28];
  const in_t* out_w   = (const in_t*)d_in[29];
  const in_t* out_b   = (const in_t*)d_in[30];
  float* out = (float*)d_out;

  // workspace carve-up (floats); total ~7.88M floats ~= 31.5 MB
  float* ws   = (float*)d_ws;
  float* hSC  = ws;                   // 8*500*32   = 128000
  float* Qb   = hSC  + 128000;        // 256000
  float* Ktb  = Qb   + 256000;        // 256000
  float* Ksum = Ktb  + 256000;        // 512
  float* G    = Ksum + 512;           // 32768
  float* lh   = G    + 32768;         // 128000
  float* A1   = lh   + 128000;        // 128000
  float* A2   = A1   + 128000;        // 128000
  float* aB   = A2   + 128000;        // 2000000
  float* cinv = aB   + 2000000;       // 4000
  float* adjb = cinv + 4000;          // 2000000
  float* dmat = adjb + 2000000;       // 250000
  float* f0   = dmat + 250000;        // 640000
  float* f1   = f0   + 640000;        // 640000
  float* f2   = f1   + 640000;        // 640000
  float* tmpF = f2   + 640000;        // 640000

  k_conv<<<dim3(4, Bz), 128, 0, stream>>>(x, conv_s_w, conv_s_b, conv_l_w, conv_l_b, hSC, f0);
  k_qk<<<dim3(16), 256, 0, stream>>>(hSC, WQ_w, WQ_b, WK_w, WK_b, Qb, Ktb);
  k_gram<<<dim3(Bz), 256, 0, stream>>>(Ktb, G, Ksum);
  k_sglob<<<dim3(2, Bz), 256, 0, stream>>>(Qb, G, Ksum, degree, tenc_w, tenc_b, senc_w, senc_b, f0);
  k_gru<<<dim3(500), 256, 0, stream>>>(x, gru_Wih, gru_Whh, gru_bih, gru_bhh, lh);
  k_a1a2<<<dim3(16), 256, 0, stream>>>(lh, W1, W2, A1, A2);
  k_dmat<<<dim3((Mn*Mn + 255)/256), 256, 0, stream>>>(d_gate, degree, dmat);
  k_pair<<<dim3(32, 32, Bz), 256, 0, stream>>>(A1, A2, Vv, b1, bv, aB);
  k_cnorm<<<dim3(4, Bz), 128, 0, stream>>>(aB, cinv);
  k_cgemm<<<dim3(8, 8, Bz), 256, 0, stream>>>(aB, cinv, Wb, wb, adj_geo, dmat, adjb);
  k_lap<<<dim3(Mn, Bz), 256, 0, stream>>>(adjb);
  // GNN layer 0
  k_spmm<<<dim3(3, 8, Bz), 256, 0, stream>>>(adjb, f0, tmpF);
  k_dense<<<dim3(3, 63), 256, 0, stream>>>(tmpF, gnn_w, gnn_b, f1);
  // GNN layer 1
  k_spmm<<<dim3(3, 8, Bz), 256, 0, stream>>>(adjb, f1, tmpF);
  k_dense<<<dim3(3, 63), 256, 0, stream>>>(tmpF, gnn_w + DF*DF, gnn_b + DF, f2);
  k_out<<<dim3(16), 256, 0, stream>>>(f0, f1, f2, lh, out_w, out_b, out);
}

// Round 4
// 534.420 us; speedup vs baseline: 1.3844x; 1.3844x over previous
//
#include <hip/hip_runtime.h>
#include <hip/hip_bf16.h>

// Problem constants
#define Bz 8
#define Tn 64
#define Mn 500
#define KC 16
#define HA 64
#define HR 64
#define NHID 32
#define DF 160
#define FINALC 512

typedef float in_t;   // reference dtypes are all float32
typedef __attribute__((ext_vector_type(8))) _Float16 half8;
typedef __attribute__((ext_vector_type(4))) float f32x4;
#define MFMAH __builtin_amdgcn_mfma_f32_16x16x32_f16

__device__ __forceinline__ float sigm(float x){ return 1.0f/(1.0f+__expf(-x)); }
__device__ __forceinline__ float tanhfast(float x){ float e=__expf(2.0f*x); return 1.0f-2.0f/(e+1.0f); }
__device__ __forceinline__ float eluf(float x){ return x>0.0f? x : (__expf(x)-1.0f); }
__device__ __forceinline__ unsigned short f2h(float f){
  _Float16 h = (_Float16)f;
  return *reinterpret_cast<unsigned short*>(&h);
}
__device__ __forceinline__ unsigned int pack2h(float a, float b){
  return (unsigned int)f2h(a) | ((unsigned int)f2h(b) << 16);
}
// split a,b into fp16 hi and fp16 lo (residual); packed dwords
__device__ __forceinline__ void pack_split(float a, float b, unsigned int& vh, unsigned int& vl){
  _Float16 ah = (_Float16)a, bh = (_Float16)b;
  float ar = a - (float)ah, br = b - (float)bh;
  vh = (unsigned int)f2h((float)ah) | ((unsigned int)f2h((float)bh) << 16);
  vl = (unsigned int)f2h(ar) | ((unsigned int)f2h(br) << 16);
}

// ---------------------------------------------------------------------------
// K1: per-node convs -> h_SC (relu), writes f0[0:32] (f32) and f0T fp16
__global__ __launch_bounds__(128) void k_conv(
    const in_t* __restrict__ x, const in_t* __restrict__ wsw, const in_t* __restrict__ wsb,
    const in_t* __restrict__ wlw, const in_t* __restrict__ wlb,
    float* __restrict__ hSC, float* __restrict__ f0, unsigned short* __restrict__ f0T)
{
  __shared__ float sw[KC*Tn];
  __shared__ float lw[KC*Tn];
  __shared__ float sb[KC], lb[KC];
  int tid = threadIdx.x;
  for (int idx = tid; idx < KC*Tn; idx += blockDim.x) {
    sw[idx] = wsw[idx];
    int k = idx >> 6, t = idx & 63;
    lw[idx] = 0.5f * wlw[k*32 + (t>>1)];
  }
  if (tid < KC) { sb[tid] = wsb[tid]; lb[tid] = wlb[tid]; }
  __syncthreads();
  int m = blockIdx.x * blockDim.x + tid;
  int b = blockIdx.y;
  if (m >= Mn) return;
  float xv[Tn];
  const in_t* xp = x + (size_t)b*Tn*Mn + m;
  #pragma unroll
  for (int t = 0; t < Tn; ++t) xv[t] = xp[t*Mn];
  float* hp = hSC + ((size_t)b*Mn + m) * (2*KC);
  float* fp = f0  + ((size_t)b*Mn + m) * DF;
  for (int k = 0; k < KC; ++k) {
    float s = 0.f, l = 0.f;
    #pragma unroll
    for (int t = 0; t < Tn; ++t) { s += xv[t]*sw[k*Tn+t]; l += xv[t]*lw[k*Tn+t]; }
    float vs = fmaxf(s + sb[k], 0.f);
    float vl = fmaxf(l + lb[k], 0.f);
    hp[k] = vs; hp[KC+k] = vl;
    fp[k] = vs; fp[KC+k] = vl;
    f0T[((size_t)b*DF + k)*Mn + m]      = f2h(vs);
    f0T[((size_t)b*DF + KC + k)*Mn + m] = f2h(vl);
  }
}

// ---------------------------------------------------------------------------
// K2: Q/K projections
__global__ __launch_bounds__(256) void k_qk(
    const float* __restrict__ hSC, const in_t* __restrict__ WQw, const in_t* __restrict__ WQb,
    const in_t* __restrict__ WKw, const in_t* __restrict__ WKb,
    float* __restrict__ Q, float* __restrict__ Kt)
{
  __shared__ float wq[HA*32], wk[HA*32], bq[HA], bk[HA];
  int tid = threadIdx.x;
  for (int i = tid; i < HA*32; i += 256) { wq[i] = WQw[i]; wk[i] = WKw[i]; }
  for (int i = tid; i < HA; i += 256) { bq[i] = WQb[i]; bk[i] = WKb[i]; }
  __syncthreads();
  int gid = blockIdx.x*256 + tid;
  if (gid >= Bz*Mn) return;
  float h[32];
  const float* hp = hSC + (size_t)gid*32;
  #pragma unroll
  for (int c = 0; c < 32; ++c) h[c] = hp[c];
  float* qp = Q + (size_t)gid*HA;
  float* kp = Kt + (size_t)gid*HA;
  for (int a = 0; a < HA; ++a) {
    float aq = bq[a], ak = bk[a];
    #pragma unroll
    for (int c = 0; c < 32; ++c) { aq += h[c]*wq[a*32+c]; ak += h[c]*wk[a*32+c]; }
    qp[a] = aq; kp[a] = ak;
  }
}

// ---------------------------------------------------------------------------
// K3: per-batch Ksum[64] and Gram G
__global__ __launch_bounds__(256) void k_gram(
    const float* __restrict__ Kt, float* __restrict__ G, float* __restrict__ Ksum)
{
  int b = blockIdx.x; int tid = threadIdx.x;
  __shared__ float L[64][HA];
  int p = tid & 63;
  int q0 = (tid >> 6) * 16;
  float acc[16];
  #pragma unroll
  for (int e = 0; e < 16; ++e) acc[e] = 0.f;
  float ks = 0.f;
  for (int m0 = 0; m0 < Mn; m0 += 64) {
    __syncthreads();
    for (int idx = tid; idx < 64*HA; idx += 256) {
      int r = idx >> 6, c = idx & 63;
      int m = m0 + r;
      L[r][c] = (m < Mn) ? Kt[((size_t)b*Mn + m)*HA + c] : 0.f;
    }
    __syncthreads();
    #pragma unroll 4
    for (int r = 0; r < 64; ++r) {
      float lp = L[r][p];
      if (tid < 64) ks += lp;
      #pragma unroll
      for (int e = 0; e < 16; ++e) acc[e] += lp * L[r][q0+e];
    }
  }
  if (tid < 64) Ksum[b*HA + tid] = ks;
  float* gp = G + (size_t)b*HA*HA;
  #pragma unroll
  for (int e = 0; e < 16; ++e) gp[p*HA + q0 + e] = acc[e];
}

// ---------------------------------------------------------------------------
// K4: s-glob + h_L, writes f0[32:160] f32 + f0T fp16
__global__ __launch_bounds__(256) void k_sglob(
    const float* __restrict__ Q, const float* __restrict__ G, const float* __restrict__ Ksum,
    const in_t* __restrict__ degree, const in_t* __restrict__ tencw, const in_t* __restrict__ tencb,
    const in_t* __restrict__ sencw, const in_t* __restrict__ sencb,
    float* __restrict__ f0, unsigned short* __restrict__ f0T)
{
  int b = blockIdx.y;
  __shared__ float Gs[HA*HA];
  __shared__ float Ks[HA], tw[HR], tb[HR], sw2[HR], sb2[HR];
  int tid = threadIdx.x;
  for (int i = tid; i < HA*HA; i += 256) Gs[i] = G[(size_t)b*HA*HA + i];
  for (int i = tid; i < HA; i += 256) {
    Ks[i] = Ksum[b*HA + i];
    tw[i] = tencw[i]; tb[i] = tencb[i];
    sw2[i] = sencw[i]; sb2[i] = sencb[i];
  }
  __syncthreads();
  int m = blockIdx.x*256 + tid;
  if (m >= Mn) return;
  const float* qp = Q + ((size_t)b*Mn + m)*HA;
  float q[HA];
  #pragma unroll
  for (int i = 0; i < HA; ++i) q[i] = qp[i];
  float rs = 0.f, qq = 0.f;
  for (int p = 0; p < HA; ++p) {
    float t = 0.f;
    #pragma unroll
    for (int c = 0; c < HA; ++c) t += Gs[p*HA + c] * q[c];
    float qpv = qp[p];
    qq += qpv * t;
    rs += qpv * Ks[p];
  }
  float nrm = fmaxf(sqrtf(fmaxf(qq, 0.f)), 1e-12f);
  float s = rs / nrm;
  float dg = degree[m];
  float* fp = f0 + ((size_t)b*Mn + m)*DF;
  for (int r = 0; r < HR; ++r) {
    float v1 = s*tw[r] + tb[r];
    float v2 = dg*sw2[r] + sb2[r];
    fp[32 + r] = v1;
    fp[96 + r] = v2;
    f0T[((size_t)b*DF + 32 + r)*Mn + m] = f2h(v1);
    f0T[((size_t)b*DF + 96 + r)*Mn + m] = f2h(v2);
  }
}

// ---------------------------------------------------------------------------
// K5: GRU
__global__ __launch_bounds__(256) void k_gru(
    const in_t* __restrict__ x, const in_t* __restrict__ Wih, const in_t* __restrict__ Whh,
    const in_t* __restrict__ bih, const in_t* __restrict__ bhh, float* __restrict__ lh)
{
  int tid = threadIdx.x;
  int lane = tid & 31;
  int seq = blockIdx.x*8 + (tid >> 5);
  int b = seq / Mn, m = seq - b*Mn;
  float wr[32], wz[32], wn[32];
  #pragma unroll
  for (int j = 0; j < 32; ++j) {
    wr[j] = Whh[(0*32 + lane)*32 + j];
    wz[j] = Whh[(32 + lane)*32 + j];
    wn[j] = Whh[(64 + lane)*32 + j];
  }
  float wir = Wih[lane],   wiz = Wih[32+lane],   win = Wih[64+lane];
  float bir = bih[lane],   biz = bih[32+lane],   bin_ = bih[64+lane];
  float bhr = bhh[lane],   bhz = bhh[32+lane],   bhn = bhh[64+lane];
  float h = 0.f;
  const in_t* xp = x + (size_t)b*Tn*Mn + m;
  for (int t = 0; t < Tn; ++t) {
    float xt = xp[t*Mn];
    float gr = bhr, gz = bhz, gn = bhn;
    #pragma unroll
    for (int j = 0; j < 32; ++j) {
      float hj = __shfl(h, j, 32);
      gr += wr[j]*hj; gz += wz[j]*hj; gn += wn[j]*hj;
    }
    float r = sigm(xt*wir + bir + gr);
    float z = sigm(xt*wiz + biz + gz);
    float n = tanhfast(xt*win + bin_ + r*gn);
    h = (1.f - z)*n + z*h;
  }
  lh[(size_t)seq*NHID + lane] = h;
}

// ---------------------------------------------------------------------------
// K6: A1/A2
__global__ __launch_bounds__(256) void k_a1a2(
    const float* __restrict__ lh, const in_t* __restrict__ W1, const in_t* __restrict__ W2,
    float* __restrict__ A1, float* __restrict__ A2)
{
  __shared__ float w1[32*32], w2[32*32];
  int tid = threadIdx.x;
  for (int i = tid; i < 1024; i += 256) { w1[i] = W1[i]; w2[i] = W2[i]; }
  __syncthreads();
  int gid = blockIdx.x*256 + tid;
  if (gid >= Bz*Mn) return;
  float h[32];
  #pragma unroll
  for (int c = 0; c < 32; ++c) h[c] = lh[(size_t)gid*32 + c];
  float* a1 = A1 + (size_t)gid*32;
  float* a2 = A2 + (size_t)gid*32;
  for (int a = 0; a < 32; ++a) {
    float s1 = 0.f, s2 = 0.f;
    #pragma unroll
    for (int c = 0; c < 32; ++c) { s1 += h[c]*w1[a*32+c]; s2 += h[c]*w2[a*32+c]; }
    a1[a] = s1; a2[a] = s2;
  }
}

// ---------------------------------------------------------------------------
// K7: dmat
__global__ __launch_bounds__(256) void k_dmat(
    const in_t* __restrict__ dgate, const in_t* __restrict__ degree, float* __restrict__ dmat)
{
  int idx = blockIdx.x*256 + threadIdx.x;
  if (idx >= Mn*Mn) return;
  int i = idx / Mn, j = idx - i*Mn;
  dmat[idx] = sigm(dgate[idx] * degree[i] * degree[j]);
}

// ---------------------------------------------------------------------------
// K8: a[b,i,j] = V . elu(A1_i + A2_j + b1) + bv   (f32 — sign feeds binarize)
__global__ __launch_bounds__(256) void k_pair(
    const float* __restrict__ A1, const float* __restrict__ A2, const in_t* __restrict__ Vv,
    const in_t* __restrict__ b1, const in_t* __restrict__ bv, float* __restrict__ aB)
{
  __shared__ float a1s[16][33], a2s[16][33], vs[32], b1s[32];
  int b = blockIdx.z;
  int i0 = blockIdx.y*16, j0 = blockIdx.x*16;
  int tid = threadIdx.x;
  if (tid < 32) { vs[tid] = Vv[tid]; b1s[tid] = b1[tid]; }
  {
    int r = tid >> 5, c = tid & 31;
    for (int rr = r; rr < 16; rr += 8) {
      int i = i0 + rr, j = j0 + rr;
      a1s[rr][c] = (i < Mn) ? A1[((size_t)b*Mn + i)*32 + c] : 0.f;
      a2s[rr][c] = (j < Mn) ? A2[((size_t)b*Mn + j)*32 + c] : 0.f;
    }
  }
  __syncthreads();
  int ti = tid >> 4, tj = tid & 15;
  int i = i0 + ti, j = j0 + tj;
  if (i >= Mn || j >= Mn) return;
  float acc = 0.f;
  #pragma unroll
  for (int c = 0; c < 32; ++c) {
    float u = a1s[ti][c] + a2s[tj][c] + b1s[c];
    acc += eluf(u) * vs[c];
  }
  aB[((size_t)b*Mn + i)*Mn + j] = acc + bv[0];
}

// ---------------------------------------------------------------------------
// K9: column inverse norms
__global__ __launch_bounds__(128) void k_cnorm(const float* __restrict__ aB, float* __restrict__ cinv)
{
  int b = blockIdx.y;
  int j = blockIdx.x*128 + threadIdx.x;
  if (j >= Mn) return;
  const float* ap = aB + (size_t)b*Mn*Mn + j;
  float ss = 0.f;
  for (int i = 0; i < Mn; ++i) { float v = ap[(size_t)i*Mn]; ss += v*v; }
  cinv[b*Mn + j] = 1.f / fmaxf(sqrtf(ss), 1e-12f);
}

// ---------------------------------------------------------------------------
// K10: c_gate GEMM via split-fp16 MFMA (3-term, ~f32 grade) + fused epilogue
__global__ __launch_bounds__(256) void k_cgemm(
    const float* __restrict__ aB, const float* __restrict__ cinv, const in_t* __restrict__ Wb,
    const in_t* __restrict__ wb, const in_t* __restrict__ adj_geo, const float* __restrict__ dmat,
    float* __restrict__ adjb)
{
  __shared__ unsigned short Ash[64*72], Asl[64*72], Bsh[64*72], Bsl[64*72];
  int b = blockIdx.z, i0 = blockIdx.y*64, j0 = blockIdx.x*64;
  int tid = threadIdx.x;
  const float* aRow = aB + (size_t)b*Mn*Mn;
  const float* civ = cinv + b*Mn;
  int w = tid >> 6, lane = tid & 63, ln = lane & 15, lg = lane >> 4;
  int wm = (w >> 1)*32, wn = (w & 1)*32;
  f32x4 acc[2][2];
  #pragma unroll
  for (int p = 0; p < 2; ++p)
    #pragma unroll
    for (int q = 0; q < 2; ++q) acc[p][q] = (f32x4)(0.f);

  for (int k0 = 0; k0 < 512; k0 += 64) {
    for (int idx = tid; idx < 2048; idx += 256) {
      int r = idx >> 5, cp = idx & 31;
      int i = i0 + r, k = k0 + 2*cp;
      unsigned int vh = 0, vl = 0;
      if (i < Mn && k < Mn)
        pack_split(aRow[(size_t)i*Mn + k]*civ[k], aRow[(size_t)i*Mn + k + 1]*civ[k+1], vh, vl);
      *reinterpret_cast<unsigned int*>(&Ash[r*72 + 2*cp]) = vh;
      *reinterpret_cast<unsigned int*>(&Asl[r*72 + 2*cp]) = vl;
    }
    for (int idx = tid; idx < 2048; idx += 256) {
      int c = idx & 63, rp = idx >> 6;
      int j = j0 + c, k = k0 + 2*rp;
      unsigned int vh = 0, vl = 0;
      if (j < Mn && k < Mn)
        pack_split(Wb[(size_t)k*Mn + j], Wb[(size_t)(k+1)*Mn + j], vh, vl);
      *reinterpret_cast<unsigned int*>(&Bsh[c*72 + 2*rp]) = vh;
      *reinterpret_cast<unsigned int*>(&Bsl[c*72 + 2*rp]) = vl;
    }
    __syncthreads();
    #pragma unroll
    for (int kk = 0; kk < 2; ++kk) {
      half8 ah0 = *reinterpret_cast<const half8*>(&Ash[(wm + 0  + ln)*72 + kk*32 + lg*8]);
      half8 ah1 = *reinterpret_cast<const half8*>(&Ash[(wm + 16 + ln)*72 + kk*32 + lg*8]);
      half8 al0 = *reinterpret_cast<const half8*>(&Asl[(wm + 0  + ln)*72 + kk*32 + lg*8]);
      half8 al1 = *reinterpret_cast<const half8*>(&Asl[(wm + 16 + ln)*72 + kk*32 + lg*8]);
      half8 bh0 = *reinterpret_cast<const half8*>(&Bsh[(wn + 0  + ln)*72 + kk*32 + lg*8]);
      half8 bh1 = *reinterpret_cast<const half8*>(&Bsh[(wn + 16 + ln)*72 + kk*32 + lg*8]);
      half8 bl0 = *reinterpret_cast<const half8*>(&Bsl[(wn + 0  + ln)*72 + kk*32 + lg*8]);
      half8 bl1 = *reinterpret_cast<const half8*>(&Bsl[(wn + 16 + ln)*72 + kk*32 + lg*8]);
      acc[0][0] = MFMAH(ah0, bh0, MFMAH(ah0, bl0, MFMAH(al0, bh0, acc[0][0], 0,0,0), 0,0,0), 0,0,0);
      acc[0][1] = MFMAH(ah0, bh1, MFMAH(ah0, bl1, MFMAH(al0, bh1, acc[0][1], 0,0,0), 0,0,0), 0,0,0);
      acc[1][0] = MFMAH(ah1, bh0, MFMAH(ah1, bl0, MFMAH(al1, bh0, acc[1][0], 0,0,0), 0,0,0), 0,0,0);
      acc[1][1] = MFMAH(ah1, bh1, MFMAH(ah1, bl1, MFMAH(al1, bh1, acc[1][1], 0,0,0), 0,0,0), 0,0,0);
    }
    __syncthreads();
  }
  float wbv = wb[0];
  #pragma unroll
  for (int mt = 0; mt < 2; ++mt)
    #pragma unroll
    for (int nt = 0; nt < 2; ++nt)
      #pragma unroll
      for (int r = 0; r < 4; ++r) {
        int i = i0 + wm + mt*16 + lg*4 + r;
        int j = j0 + wn + nt*16 + ln;
        if (i < Mn && j < Mn) {
          float cg = sigm(acc[mt][nt][r] + wbv);
          float av = aRow[(size_t)i*Mn + j]*civ[j];
          float ag = adj_geo[(size_t)i*Mn + j];
          float adjf = ag*cg + av*(1.f - cg) + dmat[(size_t)i*Mn + j]*ag;
          adjb[((size_t)b*Mn + i)*Mn + j] = (adjf > 0.f) ? 1.f : adjf;
        }
      }
}

// ---------------------------------------------------------------------------
// K11: laplace row-normalize -> fp16 lapB
__global__ __launch_bounds__(256) void k_lap(const float* __restrict__ adjb, unsigned short* __restrict__ lapB)
{
  int b = blockIdx.y, i = blockIdx.x;
  const float* row = adjb + ((size_t)b*Mn + i)*Mn;
  int tid = threadIdx.x;
  float s = 0.f;
  for (int j = tid; j < Mn; j += 256) s += row[j];
  __shared__ float red[8];
  int lane = tid & 63, wv = tid >> 6;
  #pragma unroll
  for (int off = 32; off; off >>= 1) s += __shfl_down(s, off);
  if (lane == 0) red[wv] = s;
  __syncthreads();
  if (tid == 0) {
    float d = red[0] + red[1] + red[2] + red[3];
    red[4] = (d > 0.f) ? 1.f/d : 0.f;
  }
  __syncthreads();
  float inv = red[4];
  unsigned short* lrow = lapB + ((size_t)b*Mn + i)*Mn;
  for (int j = tid; j < Mn; j += 256) lrow[j] = f2h(row[j]*inv);
}

// ---------------------------------------------------------------------------
// K12: spmm via fp16 MFMA: tmpB[b][i][d] = lapB @ fT^T
__global__ __launch_bounds__(256) void k_spmm(
    const unsigned short* __restrict__ lapB, const unsigned short* __restrict__ fT,
    unsigned short* __restrict__ tmpB)
{
  __shared__ unsigned short As[64*72], Bs[64*72];
  int b = blockIdx.z, i0 = blockIdx.y*64, j0 = blockIdx.x*64;
  int tid = threadIdx.x;
  int w = tid >> 6, lane = tid & 63, ln = lane & 15, lg = lane >> 4;
  int wm = (w >> 1)*32, wn = (w & 1)*32;
  f32x4 acc[2][2];
  #pragma unroll
  for (int p = 0; p < 2; ++p)
    #pragma unroll
    for (int q = 0; q < 2; ++q) acc[p][q] = (f32x4)(0.f);

  for (int k0 = 0; k0 < 512; k0 += 64) {
    for (int idx = tid; idx < 2048; idx += 256) {
      int r = idx >> 5, cp = idx & 31;
      int i = i0 + r, k = k0 + 2*cp;
      unsigned int v = 0;
      if (i < Mn && k < Mn)
        v = *reinterpret_cast<const unsigned int*>(&lapB[((size_t)b*Mn + i)*Mn + k]);
      *reinterpret_cast<unsigned int*>(&As[r*72 + 2*cp]) = v;
    }
    for (int idx = tid; idx < 2048; idx += 256) {
      int r = idx >> 5, cp = idx & 31;
      int d = j0 + r, k = k0 + 2*cp;
      unsigned int v = 0;
      if (d < DF && k < Mn)
        v = *reinterpret_cast<const unsigned int*>(&fT[((size_t)b*DF + d)*Mn + k]);
      *reinterpret_cast<unsigned int*>(&Bs[r*72 + 2*cp]) = v;
    }
    __syncthreads();
    #pragma unroll
    for (int kk = 0; kk < 2; ++kk) {
      half8 a0 = *reinterpret_cast<const half8*>(&As[(wm + 0  + ln)*72 + kk*32 + lg*8]);
      half8 a1 = *reinterpret_cast<const half8*>(&As[(wm + 16 + ln)*72 + kk*32 + lg*8]);
      half8 b0 = *reinterpret_cast<const half8*>(&Bs[(wn + 0  + ln)*72 + kk*32 + lg*8]);
      half8 b1 = *reinterpret_cast<const half8*>(&Bs[(wn + 16 + ln)*72 + kk*32 + lg*8]);
      acc[0][0] = MFMAH(a0, b0, acc[0][0], 0, 0, 0);
      acc[0][1] = MFMAH(a0, b1, acc[0][1], 0, 0, 0);
      acc[1][0] = MFMAH(a1, b0, acc[1][0], 0, 0, 0);
      acc[1][1] = MFMAH(a1, b1, acc[1][1], 0, 0, 0);
    }
    __syncthreads();
  }
  #pragma unroll
  for (int mt = 0; mt < 2; ++mt)
    #pragma unroll
    for (int nt = 0; nt < 2; ++nt)
      #pragma unroll
      for (int r = 0; r < 4; ++r) {
        int i = i0 + wm + mt*16 + lg*4 + r;
        int j = j0 + wn + nt*16 + ln;
        if (i < Mn && j < DF)
          tmpB[((size_t)b*Mn + i)*DF + j] = f2h(acc[mt][nt][r]);
      }
}

// ---------------------------------------------------------------------------
// K13: dense: fout = elu(tmpB @ gnn_w + bias); optional fp16 transposed copy
__global__ __launch_bounds__(256) void k_dense(
    const unsigned short* __restrict__ tmpB, const in_t* __restrict__ W, const in_t* __restrict__ bias,
    float* __restrict__ fout, unsigned short* __restrict__ foutT)
{
  __shared__ unsigned short As[64*72], Bs[64*72];
  __shared__ float bs[64];
  int i0 = blockIdx.y*64, j0 = blockIdx.x*64;
  int tid = threadIdx.x;
  if (tid < 64) bs[tid] = (j0 + tid < DF) ? bias[j0 + tid] : 0.f;
  int w = tid >> 6, lane = tid & 63, ln = lane & 15, lg = lane >> 4;
  int wm = (w >> 1)*32, wn = (w & 1)*32;
  const int NR = Bz*Mn;
  f32x4 acc[2][2];
  #pragma unroll
  for (int p = 0; p < 2; ++p)
    #pragma unroll
    for (int q = 0; q < 2; ++q) acc[p][q] = (f32x4)(0.f);

  for (int k0 = 0; k0 < 192; k0 += 64) {
    for (int idx = tid; idx < 2048; idx += 256) {
      int r = idx >> 5, cp = idx & 31;
      int i = i0 + r, k = k0 + 2*cp;
      unsigned int v = 0;
      if (i < NR && k < DF)
        v = *reinterpret_cast<const unsigned int*>(&tmpB[(size_t)i*DF + k]);
      *reinterpret_cast<unsigned int*>(&As[r*72 + 2*cp]) = v;
    }
    for (int idx = tid; idx < 2048; idx += 256) {
      int c = idx & 63, rp = idx >> 6;
      int j = j0 + c, k = k0 + 2*rp;
      unsigned int v = 0;
      if (j < DF && k < DF)
        v = pack2h(W[(size_t)k*DF + j], W[(size_t)(k+1)*DF + j]);
      *reinterpret_cast<unsigned int*>(&Bs[c*72 + 2*rp]) = v;
    }
    __syncthreads();
    #pragma unroll
    for (int kk = 0; kk < 2; ++kk) {
      half8 a0 = *reinterpret_cast<const half8*>(&As[(wm + 0  + ln)*72 + kk*32 + lg*8]);
      half8 a1 = *reinterpret_cast<const half8*>(&As[(wm + 16 + ln)*72 + kk*32 + lg*8]);
      half8 b0 = *reinterpret_cast<const half8*>(&Bs[(wn + 0  + ln)*72 + kk*32 + lg*8]);
      half8 b1 = *reinterpret_cast<const half8*>(&Bs[(wn + 16 + ln)*72 + kk*32 + lg*8]);
      acc[0][0] = MFMAH(a0, b0, acc[0][0], 0, 0, 0);
      acc[0][1] = MFMAH(a0, b1, acc[0][1], 0, 0, 0);
      acc[1][0] = MFMAH(a1, b0, acc[1][0], 0, 0, 0);
      acc[1][1] = MFMAH(a1, b1, acc[1][1], 0, 0, 0);
    }
    __syncthreads();
  }
  #pragma unroll
  for (int mt = 0; mt < 2; ++mt)
    #pragma unroll
    for (int nt = 0; nt < 2; ++nt)
      #pragma unroll
      for (int r = 0; r < 4; ++r) {
        int i = i0 + wm + mt*16 + lg*4 + r;
        int jl = wn + nt*16 + ln;
        int j = j0 + jl;
        if (i < NR && j < DF) {
          float val = eluf(acc[mt][nt][r] + bs[jl]);
          fout[(size_t)i*DF + j] = val;
          if (foutT) {
            int bb = i / Mn, mm = i - bb*Mn;
            foutT[((size_t)bb*DF + j)*Mn + mm] = f2h(val);
          }
        }
      }
}

// ---------------------------------------------------------------------------
// K14: output projection
__global__ __launch_bounds__(256) void k_out(
    const float* __restrict__ f0, const float* __restrict__ f1, const float* __restrict__ f2,
    const float* __restrict__ lh, const in_t* __restrict__ ow, const in_t* __restrict__ ob,
    float* __restrict__ outp)
{
  __shared__ float w[FINALC];
  int tid = threadIdx.x;
  for (int i = tid; i < FINALC; i += 256) w[i] = ow[i];
  __syncthreads();
  int gid = blockIdx.x*256 + tid;
  if (gid >= Bz*Mn) return;
  float s = ob[0];
  const float* p0 = f0 + (size_t)gid*DF;
  const float* p1 = f1 + (size_t)gid*DF;
  const float* p2 = f2 + (size_t)gid*DF;
  const float* pl = lh + (size_t)gid*NHID;
  for (int c = 0; c < DF; ++c) s += p0[c]*w[c];
  for (int c = 0; c < DF; ++c) s += p1[c]*w[DF + c];
  for (int c = 0; c < DF; ++c) s += p2[c]*w[2*DF + c];
  for (int c = 0; c < NHID; ++c) s += pl[c]*w[3*DF + c];
  outp[gid] = s;
}

// ---------------------------------------------------------------------------
extern "C" void kernel_launch(void* const* d_in, const int* in_sizes, int n_in,
                              void* d_out, int out_size, void* d_ws, size_t ws_size,
                              hipStream_t stream)
{
  const in_t* x       = (const in_t*)d_in[0];
  const in_t* adj_geo = (const in_t*)d_in[1];
  const in_t* degree  = (const in_t*)d_in[2];
  const in_t* conv_s_w= (const in_t*)d_in[3];
  const in_t* conv_s_b= (const in_t*)d_in[4];
  const in_t* conv_l_w= (const in_t*)d_in[5];
  const in_t* conv_l_b= (const in_t*)d_in[6];
  const in_t* WQ_w    = (const in_t*)d_in[7];
  const in_t* WQ_b    = (const in_t*)d_in[8];
  const in_t* WK_w    = (const in_t*)d_in[9];
  const in_t* WK_b    = (const in_t*)d_in[10];
  const in_t* tenc_w  = (const in_t*)d_in[11];
  const in_t* tenc_b  = (const in_t*)d_in[12];
  const in_t* senc_w  = (const in_t*)d_in[13];
  const in_t* senc_b  = (const in_t*)d_in[14];
  const in_t* gru_Wih = (const in_t*)d_in[15];
  const in_t* gru_Whh = (const in_t*)d_in[16];
  const in_t* gru_bih = (const in_t*)d_in[17];
  const in_t* gru_bhh = (const in_t*)d_in[18];
  const in_t* Vv      = (const in_t*)d_in[19];
  const in_t* W1      = (const in_t*)d_in[20];
  const in_t* W2      = (const in_t*)d_in[21];
  const in_t* Wb      = (const in_t*)d_in[22];
  const in_t* bv      = (const in_t*)d_in[23];
  const in_t* b1      = (const in_t*)d_in[24];
  const in_t* wb      = (const in_t*)d_in[25];
  const in_t* d_gate  = (const in_t*)d_in[26];
  const in_t* gnn_w   = (const in_t*)d_in[27];
  const in_t* gnn_b   = (const in_t*)d_in[28];
  const in_t* out_w   = (const in_t*)d_in[29];
  const in_t* out_b   = (const in_t*)d_in[30];
  float* out = (float*)d_out;

  // workspace carve-up (float offsets); total 8,191,280 floats ~= 32.8 MB
  float* ws   = (float*)d_ws;
  float* hSC  = ws;                    // 128000
  float* Qb   = ws + 128000;           // 256000
  float* Ktb  = ws + 384000;           // 256000
  float* Ksum = ws + 640000;           // 512
  float* G    = ws + 640512;           // 32768
  float* lh   = ws + 673280;           // 128000
  float* A1   = ws + 801280;           // 128000
  float* A2   = ws + 929280;           // 128000
  float* aB   = ws + 1057280;          // 2000000 (dead after k_cgemm; lapB overlays)
  float* cinv = ws + 3057280;          // 4000
  float* adjb = ws + 3061280;          // 2000000
  float* dmat = ws + 5061280;          // 250000
  float* f0   = ws + 5311280;          // 640000
  float* f1   = ws + 5951280;          // 640000
  float* f2   = ws + 6591280;          // 640000
  unsigned short* f0T  = (unsigned short*)(ws + 7231280);  // 640000 fp16
  unsigned short* tmpB = (unsigned short*)(ws + 7551280);  // 640000 fp16
  unsigned short* f1T  = (unsigned short*)(ws + 7871280);  // 640000 fp16
  unsigned short* lapB = (unsigned short*)aB;              // 2000000 fp16 (overlay, safe: aB dead)

  k_conv<<<dim3(4, Bz), 128, 0, stream>>>(x, conv_s_w, conv_s_b, conv_l_w, conv_l_b, hSC, f0, f0T);
  k_qk<<<dim3(16), 256, 0, stream>>>(hSC, WQ_w, WQ_b, WK_w, WK_b, Qb, Ktb);
  k_gram<<<dim3(Bz), 256, 0, stream>>>(Ktb, G, Ksum);
  k_sglob<<<dim3(2, Bz), 256, 0, stream>>>(Qb, G, Ksum, degree, tenc_w, tenc_b, senc_w, senc_b, f0, f0T);
  k_gru<<<dim3(500), 256, 0, stream>>>(x, gru_Wih, gru_Whh, gru_bih, gru_bhh, lh);
  k_a1a2<<<dim3(16), 256, 0, stream>>>(lh, W1, W2, A1, A2);
  k_dmat<<<dim3((Mn*Mn + 255)/256), 256, 0, stream>>>(d_gate, degree, dmat);
  k_pair<<<dim3(32, 32, Bz), 256, 0, stream>>>(A1, A2, Vv, b1, bv, aB);
  k_cnorm<<<dim3(4, Bz), 128, 0, stream>>>(aB, cinv);
  k_cgemm<<<dim3(8, 8, Bz), 256, 0, stream>>>(aB, cinv, Wb, wb, adj_geo, dmat, adjb);
  k_lap<<<dim3(Mn, Bz), 256, 0, stream>>>(adjb, lapB);
  // GNN layer 0
  k_spmm<<<dim3(3, 8, Bz), 256, 0, stream>>>(lapB, f0T, tmpB);
  k_dense<<<dim3(3, 63), 256, 0, stream>>>(tmpB, gnn_w, gnn_b, f1, f1T);
  // GNN layer 1
  k_spmm<<<dim3(3, 8, Bz), 256, 0, stream>>>(lapB, f1T, tmpB);
  k_dense<<<dim3(3, 63), 256, 0, stream>>>(tmpB, gnn_w + DF*DF, gnn_b + DF, f2, (unsigned short*)nullptr);
  k_out<<<dim3(16), 256, 0, stream>>>(f0, f1, f2, lh, out_w, out_b, out);
}

// Round 5
// 454.581 us; speedup vs baseline: 1.6275x; 1.1756x over previous
//
#include <hip/hip_runtime.h>
#include <hip/hip_bf16.h>

// Problem constants
#define Bz 8
#define Tn 64
#define Mn 500
#define KC 16
#define HA 64
#define HR 64
#define NHID 32
#define DF 160
#define FINALC 512
#define GSPLIT 8

typedef float in_t;   // reference dtypes are all float32
typedef __attribute__((ext_vector_type(8))) _Float16 half8;
typedef __attribute__((ext_vector_type(4))) float f32x4;
#define MFMAH __builtin_amdgcn_mfma_f32_16x16x32_f16

__device__ __forceinline__ float sigm(float x){ return 1.0f/(1.0f+__expf(-x)); }
__device__ __forceinline__ float tanhfast(float x){ float e=__expf(2.0f*x); return 1.0f-2.0f/(e+1.0f); }
__device__ __forceinline__ float eluf(float x){ return x>0.0f? x : (__expf(x)-1.0f); }
__device__ __forceinline__ unsigned short f2h(float f){
  _Float16 h = (_Float16)f;
  return *reinterpret_cast<unsigned short*>(&h);
}
__device__ __forceinline__ unsigned int pack2h(float a, float b){
  return (unsigned int)f2h(a) | ((unsigned int)f2h(b) << 16);
}
// split a,b into fp16 hi and fp16 lo (residual); packed dwords
__device__ __forceinline__ void pack_split(float a, float b, unsigned int& vh, unsigned int& vl){
  _Float16 ah = (_Float16)a, bh = (_Float16)b;
  float ar = a - (float)ah, br = b - (float)bh;
  vh = (unsigned int)f2h((float)ah) | ((unsigned int)f2h((float)bh) << 16);
  vl = (unsigned int)f2h(ar) | ((unsigned int)f2h(br) << 16);
}

// ---------------------------------------------------------------------------
// K1: per-node convs -> h_SC (relu), writes f0[0:32] (f32) and f0T fp16
__global__ __launch_bounds__(128) void k_conv(
    const in_t* __restrict__ x, const in_t* __restrict__ wsw, const in_t* __restrict__ wsb,
    const in_t* __restrict__ wlw, const in_t* __restrict__ wlb,
    float* __restrict__ hSC, float* __restrict__ f0, unsigned short* __restrict__ f0T)
{
  __shared__ float sw[KC*Tn];
  __shared__ float lw[KC*Tn];
  __shared__ float sb[KC], lb[KC];
  int tid = threadIdx.x;
  for (int idx = tid; idx < KC*Tn; idx += blockDim.x) {
    sw[idx] = wsw[idx];
    int k = idx >> 6, t = idx & 63;
    lw[idx] = 0.5f * wlw[k*32 + (t>>1)];
  }
  if (tid < KC) { sb[tid] = wsb[tid]; lb[tid] = wlb[tid]; }
  __syncthreads();
  int m = blockIdx.x * blockDim.x + tid;
  int b = blockIdx.y;
  if (m >= Mn) return;
  float xv[Tn];
  const in_t* xp = x + (size_t)b*Tn*Mn + m;
  #pragma unroll
  for (int t = 0; t < Tn; ++t) xv[t] = xp[t*Mn];
  float* hp = hSC + ((size_t)b*Mn + m) * (2*KC);
  float* fp = f0  + ((size_t)b*Mn + m) * DF;
  for (int k = 0; k < KC; ++k) {
    float s = 0.f, l = 0.f;
    #pragma unroll
    for (int t = 0; t < Tn; ++t) { s += xv[t]*sw[k*Tn+t]; l += xv[t]*lw[k*Tn+t]; }
    float vs = fmaxf(s + sb[k], 0.f);
    float vl = fmaxf(l + lb[k], 0.f);
    hp[k] = vs; hp[KC+k] = vl;
    fp[k] = vs; fp[KC+k] = vl;
    f0T[((size_t)b*DF + k)*Mn + m]      = f2h(vs);
    f0T[((size_t)b*DF + KC + k)*Mn + m] = f2h(vl);
  }
}

// ---------------------------------------------------------------------------
// K2: Q/K projections
__global__ __launch_bounds__(256) void k_qk(
    const float* __restrict__ hSC, const in_t* __restrict__ WQw, const in_t* __restrict__ WQb,
    const in_t* __restrict__ WKw, const in_t* __restrict__ WKb,
    float* __restrict__ Q, float* __restrict__ Kt)
{
  __shared__ float wq[HA*32], wk[HA*32], bq[HA], bk[HA];
  int tid = threadIdx.x;
  for (int i = tid; i < HA*32; i += 256) { wq[i] = WQw[i]; wk[i] = WKw[i]; }
  for (int i = tid; i < HA; i += 256) { bq[i] = WQb[i]; bk[i] = WKb[i]; }
  __syncthreads();
  int gid = blockIdx.x*256 + tid;
  if (gid >= Bz*Mn) return;
  float h[32];
  const float* hp = hSC + (size_t)gid*32;
  #pragma unroll
  for (int c = 0; c < 32; ++c) h[c] = hp[c];
  float* qp = Q + (size_t)gid*HA;
  float* kp = Kt + (size_t)gid*HA;
  for (int a = 0; a < HA; ++a) {
    float aq = bq[a], ak = bk[a];
    #pragma unroll
    for (int c = 0; c < 32; ++c) { aq += h[c]*wq[a*32+c]; ak += h[c]*wk[a*32+c]; }
    qp[a] = aq; kp[a] = ak;
  }
}

// ---------------------------------------------------------------------------
// K3: split-K partial Gram: Gpart[(split*Bz+b)] = sum_{m in chunk} K_m K_m^T
// grid (GSPLIT, Bz); deterministic (plain stores, summed in k_sglob)
__global__ __launch_bounds__(256) void k_gram(
    const float* __restrict__ Kt, float* __restrict__ Gpart, float* __restrict__ Kpart)
{
  int split = blockIdx.x, b = blockIdx.y;
  int tid = threadIdx.x;
  __shared__ float L[64][HA];
  int m0 = split*63;
  int mend = min(m0 + 63, Mn);
  int p = tid & 63;
  int q0 = (tid >> 6) * 16;
  float acc[16];
  #pragma unroll
  for (int e = 0; e < 16; ++e) acc[e] = 0.f;
  for (int idx = tid; idx < 64*HA; idx += 256) {
    int r = idx >> 6, c = idx & 63;
    int m = m0 + r;
    L[r][c] = (m < mend) ? Kt[((size_t)b*Mn + m)*HA + c] : 0.f;
  }
  __syncthreads();
  float ks = 0.f;
  #pragma unroll 4
  for (int r = 0; r < 63; ++r) {
    float lp = L[r][p];
    if (tid < 64) ks += lp;
    #pragma unroll
    for (int e = 0; e < 16; ++e) acc[e] += lp * L[r][q0+e];
  }
  float* gp = Gpart + ((size_t)split*Bz + b)*HA*HA;
  #pragma unroll
  for (int e = 0; e < 16; ++e) gp[p*HA + q0 + e] = acc[e];
  if (tid < 64) Kpart[((size_t)split*Bz + b)*HA + tid] = ks;
}

// ---------------------------------------------------------------------------
// K4: s-glob + h_L (sums the GSPLIT partials on load), writes f0[32:160]
__global__ __launch_bounds__(256) void k_sglob(
    const float* __restrict__ Q, const float* __restrict__ Gpart, const float* __restrict__ Kpart,
    const in_t* __restrict__ degree, const in_t* __restrict__ tencw, const in_t* __restrict__ tencb,
    const in_t* __restrict__ sencw, const in_t* __restrict__ sencb,
    float* __restrict__ f0, unsigned short* __restrict__ f0T)
{
  int b = blockIdx.y;
  __shared__ float Gs[HA*HA];
  __shared__ float Ks[HA], tw[HR], tb[HR], sw2[HR], sb2[HR];
  int tid = threadIdx.x;
  for (int i = tid; i < HA*HA; i += 256) {
    float s = 0.f;
    #pragma unroll
    for (int sp = 0; sp < GSPLIT; ++sp) s += Gpart[((size_t)sp*Bz + b)*HA*HA + i];
    Gs[i] = s;
  }
  for (int i = tid; i < HA; i += 256) {
    float s = 0.f;
    #pragma unroll
    for (int sp = 0; sp < GSPLIT; ++sp) s += Kpart[((size_t)sp*Bz + b)*HA + i];
    Ks[i] = s;
    tw[i] = tencw[i]; tb[i] = tencb[i];
    sw2[i] = sencw[i]; sb2[i] = sencb[i];
  }
  __syncthreads();
  int m = blockIdx.x*256 + tid;
  if (m >= Mn) return;
  const float* qp = Q + ((size_t)b*Mn + m)*HA;
  float q[HA];
  #pragma unroll
  for (int i = 0; i < HA; ++i) q[i] = qp[i];
  float rs = 0.f, qq = 0.f;
  for (int p = 0; p < HA; ++p) {
    float t = 0.f;
    #pragma unroll
    for (int c = 0; c < HA; ++c) t += Gs[p*HA + c] * q[c];
    float qpv = qp[p];
    qq += qpv * t;
    rs += qpv * Ks[p];
  }
  float nrm = fmaxf(sqrtf(fmaxf(qq, 0.f)), 1e-12f);
  float s = rs / nrm;
  float dg = degree[m];
  float* fp = f0 + ((size_t)b*Mn + m)*DF;
  for (int r = 0; r < HR; ++r) {
    float v1 = s*tw[r] + tb[r];
    float v2 = dg*sw2[r] + sb2[r];
    fp[32 + r] = v1;
    fp[96 + r] = v2;
    f0T[((size_t)b*DF + 32 + r)*Mn + m] = f2h(v1);
    f0T[((size_t)b*DF + 96 + r)*Mn + m] = f2h(v2);
  }
}

// ---------------------------------------------------------------------------
// K5: GRU
__global__ __launch_bounds__(256) void k_gru(
    const in_t* __restrict__ x, const in_t* __restrict__ Wih, const in_t* __restrict__ Whh,
    const in_t* __restrict__ bih, const in_t* __restrict__ bhh, float* __restrict__ lh)
{
  int tid = threadIdx.x;
  int lane = tid & 31;
  int seq = blockIdx.x*8 + (tid >> 5);
  int b = seq / Mn, m = seq - b*Mn;
  float wr[32], wz[32], wn[32];
  #pragma unroll
  for (int j = 0; j < 32; ++j) {
    wr[j] = Whh[(0*32 + lane)*32 + j];
    wz[j] = Whh[(32 + lane)*32 + j];
    wn[j] = Whh[(64 + lane)*32 + j];
  }
  float wir = Wih[lane],   wiz = Wih[32+lane],   win = Wih[64+lane];
  float bir = bih[lane],   biz = bih[32+lane],   bin_ = bih[64+lane];
  float bhr = bhh[lane],   bhz = bhh[32+lane],   bhn = bhh[64+lane];
  float h = 0.f;
  const in_t* xp = x + (size_t)b*Tn*Mn + m;
  for (int t = 0; t < Tn; ++t) {
    float xt = xp[t*Mn];
    float gr = bhr, gz = bhz, gn = bhn;
    #pragma unroll
    for (int j = 0; j < 32; ++j) {
      float hj = __shfl(h, j, 32);
      gr += wr[j]*hj; gz += wz[j]*hj; gn += wn[j]*hj;
    }
    float r = sigm(xt*wir + bir + gr);
    float z = sigm(xt*wiz + biz + gz);
    float n = tanhfast(xt*win + bin_ + r*gn);
    h = (1.f - z)*n + z*h;
  }
  lh[(size_t)seq*NHID + lane] = h;
}

// ---------------------------------------------------------------------------
// K6: A1/A2
__global__ __launch_bounds__(256) void k_a1a2(
    const float* __restrict__ lh, const in_t* __restrict__ W1, const in_t* __restrict__ W2,
    float* __restrict__ A1, float* __restrict__ A2)
{
  __shared__ float w1[32*32], w2[32*32];
  int tid = threadIdx.x;
  for (int i = tid; i < 1024; i += 256) { w1[i] = W1[i]; w2[i] = W2[i]; }
  __syncthreads();
  int gid = blockIdx.x*256 + tid;
  if (gid >= Bz*Mn) return;
  float h[32];
  #pragma unroll
  for (int c = 0; c < 32; ++c) h[c] = lh[(size_t)gid*32 + c];
  float* a1 = A1 + (size_t)gid*32;
  float* a2 = A2 + (size_t)gid*32;
  for (int a = 0; a < 32; ++a) {
    float s1 = 0.f, s2 = 0.f;
    #pragma unroll
    for (int c = 0; c < 32; ++c) { s1 += h[c]*w1[a*32+c]; s2 += h[c]*w2[a*32+c]; }
    a1[a] = s1; a2[a] = s2;
  }
}

// ---------------------------------------------------------------------------
// K7: dmat
__global__ __launch_bounds__(256) void k_dmat(
    const in_t* __restrict__ dgate, const in_t* __restrict__ degree, float* __restrict__ dmat)
{
  int idx = blockIdx.x*256 + threadIdx.x;
  if (idx >= Mn*Mn) return;
  int i = idx / Mn, j = idx - i*Mn;
  dmat[idx] = sigm(dgate[idx] * degree[i] * degree[j]);
}

// ---------------------------------------------------------------------------
// K8: a[b,i,j] = V . elu(A1_i + A2_j + b1) + bv   (f32 — sign feeds binarize)
__global__ __launch_bounds__(256) void k_pair(
    const float* __restrict__ A1, const float* __restrict__ A2, const in_t* __restrict__ Vv,
    const in_t* __restrict__ b1, const in_t* __restrict__ bv, float* __restrict__ aB)
{
  __shared__ float a1s[16][33], a2s[16][33], vs[32], b1s[32];
  int b = blockIdx.z;
  int i0 = blockIdx.y*16, j0 = blockIdx.x*16;
  int tid = threadIdx.x;
  if (tid < 32) { vs[tid] = Vv[tid]; b1s[tid] = b1[tid]; }
  {
    int r = tid >> 5, c = tid & 31;
    for (int rr = r; rr < 16; rr += 8) {
      int i = i0 + rr, j = j0 + rr;
      a1s[rr][c] = (i < Mn) ? A1[((size_t)b*Mn + i)*32 + c] : 0.f;
      a2s[rr][c] = (j < Mn) ? A2[((size_t)b*Mn + j)*32 + c] : 0.f;
    }
  }
  __syncthreads();
  int ti = tid >> 4, tj = tid & 15;
  int i = i0 + ti, j = j0 + tj;
  if (i >= Mn || j >= Mn) return;
  float acc = 0.f;
  #pragma unroll
  for (int c = 0; c < 32; ++c) {
    float u = a1s[ti][c] + a2s[tj][c] + b1s[c];
    acc += eluf(u) * vs[c];
  }
  aB[((size_t)b*Mn + i)*Mn + j] = acc + bv[0];
}

// ---------------------------------------------------------------------------
// K9a: partial column sum-squares over row chunks; grid (4 jblk, 8 isplit, Bz)
__global__ __launch_bounds__(128) void k_cnorm(const float* __restrict__ aB, float* __restrict__ ssp)
{
  int jb = blockIdx.x, isp = blockIdx.y, b = blockIdx.z;
  int j = jb*128 + threadIdx.x;
  if (j >= Mn) return;
  int i0 = isp*63, iend = min(i0 + 63, Mn);
  const float* ap = aB + (size_t)b*Mn*Mn + j;
  float ss = 0.f;
  for (int i = i0; i < iend; ++i) { float v = ap[(size_t)i*Mn]; ss += v*v; }
  ssp[((size_t)isp*Bz + b)*Mn + j] = ss;
}

// K9b: finalize cinv = 1/max(sqrt(sum ssp),1e-12)
__global__ __launch_bounds__(256) void k_cfin(const float* __restrict__ ssp, float* __restrict__ cinv)
{
  int idx = blockIdx.x*256 + threadIdx.x;
  if (idx >= Bz*Mn) return;
  int b = idx / Mn, j = idx - b*Mn;
  float ss = 0.f;
  #pragma unroll
  for (int sp = 0; sp < 8; ++sp) ss += ssp[((size_t)sp*Bz + b)*Mn + j];
  cinv[idx] = 1.f / fmaxf(sqrtf(ss), 1e-12f);
}

// ---------------------------------------------------------------------------
// K10: c_gate GEMM via split-fp16 MFMA (3-term, ~f32 grade) + fused epilogue
__global__ __launch_bounds__(256) void k_cgemm(
    const float* __restrict__ aB, const float* __restrict__ cinv, const in_t* __restrict__ Wb,
    const in_t* __restrict__ wb, const in_t* __restrict__ adj_geo, const float* __restrict__ dmat,
    float* __restrict__ adjb)
{
  __shared__ unsigned short Ash[64*72], Asl[64*72], Bsh[64*72], Bsl[64*72];
  int b = blockIdx.z, i0 = blockIdx.y*64, j0 = blockIdx.x*64;
  int tid = threadIdx.x;
  const float* aRow = aB + (size_t)b*Mn*Mn;
  const float* civ = cinv + b*Mn;
  int w = tid >> 6, lane = tid & 63, ln = lane & 15, lg = lane >> 4;
  int wm = (w >> 1)*32, wn = (w & 1)*32;
  f32x4 acc[2][2];
  #pragma unroll
  for (int p = 0; p < 2; ++p)
    #pragma unroll
    for (int q = 0; q < 2; ++q) acc[p][q] = (f32x4)(0.f);

  for (int k0 = 0; k0 < 512; k0 += 64) {
    for (int idx = tid; idx < 2048; idx += 256) {
      int r = idx >> 5, cp = idx & 31;
      int i = i0 + r, k = k0 + 2*cp;
      unsigned int vh = 0, vl = 0;
      if (i < Mn && k < Mn)
        pack_split(aRow[(size_t)i*Mn + k]*civ[k], aRow[(size_t)i*Mn + k + 1]*civ[k+1], vh, vl);
      *reinterpret_cast<unsigned int*>(&Ash[r*72 + 2*cp]) = vh;
      *reinterpret_cast<unsigned int*>(&Asl[r*72 + 2*cp]) = vl;
    }
    for (int idx = tid; idx < 2048; idx += 256) {
      int c = idx & 63, rp = idx >> 6;
      int j = j0 + c, k = k0 + 2*rp;
      unsigned int vh = 0, vl = 0;
      if (j < Mn && k < Mn)
        pack_split(Wb[(size_t)k*Mn + j], Wb[(size_t)(k+1)*Mn + j], vh, vl);
      *reinterpret_cast<unsigned int*>(&Bsh[c*72 + 2*rp]) = vh;
      *reinterpret_cast<unsigned int*>(&Bsl[c*72 + 2*rp]) = vl;
    }
    __syncthreads();
    #pragma unroll
    for (int kk = 0; kk < 2; ++kk) {
      half8 ah0 = *reinterpret_cast<const half8*>(&Ash[(wm + 0  + ln)*72 + kk*32 + lg*8]);
      half8 ah1 = *reinterpret_cast<const half8*>(&Ash[(wm + 16 + ln)*72 + kk*32 + lg*8]);
      half8 al0 = *reinterpret_cast<const half8*>(&Asl[(wm + 0  + ln)*72 + kk*32 + lg*8]);
      half8 al1 = *reinterpret_cast<const half8*>(&Asl[(wm + 16 + ln)*72 + kk*32 + lg*8]);
      half8 bh0 = *reinterpret_cast<const half8*>(&Bsh[(wn + 0  + ln)*72 + kk*32 + lg*8]);
      half8 bh1 = *reinterpret_cast<const half8*>(&Bsh[(wn + 16 + ln)*72 + kk*32 + lg*8]);
      half8 bl0 = *reinterpret_cast<const half8*>(&Bsl[(wn + 0  + ln)*72 + kk*32 + lg*8]);
      half8 bl1 = *reinterpret_cast<const half8*>(&Bsl[(wn + 16 + ln)*72 + kk*32 + lg*8]);
      acc[0][0] = MFMAH(ah0, bh0, MFMAH(ah0, bl0, MFMAH(al0, bh0, acc[0][0], 0,0,0), 0,0,0), 0,0,0);
      acc[0][1] = MFMAH(ah0, bh1, MFMAH(ah0, bl1, MFMAH(al0, bh1, acc[0][1], 0,0,0), 0,0,0), 0,0,0);
      acc[1][0] = MFMAH(ah1, bh0, MFMAH(ah1, bl0, MFMAH(al1, bh0, acc[1][0], 0,0,0), 0,0,0), 0,0,0);
      acc[1][1] = MFMAH(ah1, bh1, MFMAH(ah1, bl1, MFMAH(al1, bh1, acc[1][1], 0,0,0), 0,0,0), 0,0,0);
    }
    __syncthreads();
  }
  float wbv = wb[0];
  #pragma unroll
  for (int mt = 0; mt < 2; ++mt)
    #pragma unroll
    for (int nt = 0; nt < 2; ++nt)
      #pragma unroll
      for (int r = 0; r < 4; ++r) {
        int i = i0 + wm + mt*16 + lg*4 + r;
        int j = j0 + wn + nt*16 + ln;
        if (i < Mn && j < Mn) {
          float cg = sigm(acc[mt][nt][r] + wbv);
          float av = aRow[(size_t)i*Mn + j]*civ[j];
          float ag = adj_geo[(size_t)i*Mn + j];
          float adjf = ag*cg + av*(1.f - cg) + dmat[(size_t)i*Mn + j]*ag;
          adjb[((size_t)b*Mn + i)*Mn + j] = (adjf > 0.f) ? 1.f : adjf;
        }
      }
}

// ---------------------------------------------------------------------------
// K11: laplace row-normalize -> fp16 lapB
__global__ __launch_bounds__(256) void k_lap(const float* __restrict__ adjb, unsigned short* __restrict__ lapB)
{
  int b = blockIdx.y, i = blockIdx.x;
  const float* row = adjb + ((size_t)b*Mn + i)*Mn;
  int tid = threadIdx.x;
  float s = 0.f;
  for (int j = tid; j < Mn; j += 256) s += row[j];
  __shared__ float red[8];
  int lane = tid & 63, wv = tid >> 6;
  #pragma unroll
  for (int off = 32; off; off >>= 1) s += __shfl_down(s, off);
  if (lane == 0) red[wv] = s;
  __syncthreads();
  if (tid == 0) {
    float d = red[0] + red[1] + red[2] + red[3];
    red[4] = (d > 0.f) ? 1.f/d : 0.f;
  }
  __syncthreads();
  float inv = red[4];
  unsigned short* lrow = lapB + ((size_t)b*Mn + i)*Mn;
  for (int j = tid; j < Mn; j += 256) lrow[j] = f2h(row[j]*inv);
}

// ---------------------------------------------------------------------------
// K12: spmm via fp16 MFMA: tmpB[b][i][d] = lapB @ fT^T
__global__ __launch_bounds__(256) void k_spmm(
    const unsigned short* __restrict__ lapB, const unsigned short* __restrict__ fT,
    unsigned short* __restrict__ tmpB)
{
  __shared__ unsigned short As[64*72], Bs[64*72];
  int b = blockIdx.z, i0 = blockIdx.y*64, j0 = blockIdx.x*64;
  int tid = threadIdx.x;
  int w = tid >> 6, lane = tid & 63, ln = lane & 15, lg = lane >> 4;
  int wm = (w >> 1)*32, wn = (w & 1)*32;
  f32x4 acc[2][2];
  #pragma unroll
  for (int p = 0; p < 2; ++p)
    #pragma unroll
    for (int q = 0; q < 2; ++q) acc[p][q] = (f32x4)(0.f);

  for (int k0 = 0; k0 < 512; k0 += 64) {
    for (int idx = tid; idx < 2048; idx += 256) {
      int r = idx >> 5, cp = idx & 31;
      int i = i0 + r, k = k0 + 2*cp;
      unsigned int v = 0;
      if (i < Mn && k < Mn)
        v = *reinterpret_cast<const unsigned int*>(&lapB[((size_t)b*Mn + i)*Mn + k]);
      *reinterpret_cast<unsigned int*>(&As[r*72 + 2*cp]) = v;
    }
    for (int idx = tid; idx < 2048; idx += 256) {
      int r = idx >> 5, cp = idx & 31;
      int d = j0 + r, k = k0 + 2*cp;
      unsigned int v = 0;
      if (d < DF && k < Mn)
        v = *reinterpret_cast<const unsigned int*>(&fT[((size_t)b*DF + d)*Mn + k]);
      *reinterpret_cast<unsigned int*>(&Bs[r*72 + 2*cp]) = v;
    }
    __syncthreads();
    #pragma unroll
    for (int kk = 0; kk < 2; ++kk) {
      half8 a0 = *reinterpret_cast<const half8*>(&As[(wm + 0  + ln)*72 + kk*32 + lg*8]);
      half8 a1 = *reinterpret_cast<const half8*>(&As[(wm + 16 + ln)*72 + kk*32 + lg*8]);
      half8 b0 = *reinterpret_cast<const half8*>(&Bs[(wn + 0  + ln)*72 + kk*32 + lg*8]);
      half8 b1 = *reinterpret_cast<const half8*>(&Bs[(wn + 16 + ln)*72 + kk*32 + lg*8]);
      acc[0][0] = MFMAH(a0, b0, acc[0][0], 0, 0, 0);
      acc[0][1] = MFMAH(a0, b1, acc[0][1], 0, 0, 0);
      acc[1][0] = MFMAH(a1, b0, acc[1][0], 0, 0, 0);
      acc[1][1] = MFMAH(a1, b1, acc[1][1], 0, 0, 0);
    }
    __syncthreads();
  }
  #pragma unroll
  for (int mt = 0; mt < 2; ++mt)
    #pragma unroll
    for (int nt = 0; nt < 2; ++nt)
      #pragma unroll
      for (int r = 0; r < 4; ++r) {
        int i = i0 + wm + mt*16 + lg*4 + r;
        int j = j0 + wn + nt*16 + ln;
        if (i < Mn && j < DF)
          tmpB[((size_t)b*Mn + i)*DF + j] = f2h(acc[mt][nt][r]);
      }
}

// ---------------------------------------------------------------------------
// K13: dense: fout = elu(tmpB @ gnn_w + bias); optional fp16 transposed copy
__global__ __launch_bounds__(256) void k_dense(
    const unsigned short* __restrict__ tmpB, const in_t* __restrict__ W, const in_t* __restrict__ bias,
    float* __restrict__ fout, unsigned short* __restrict__ foutT)
{
  __shared__ unsigned short As[64*72], Bs[64*72];
  __shared__ float bs[64];
  int i0 = blockIdx.y*64, j0 = blockIdx.x*64;
  int tid = threadIdx.x;
  if (tid < 64) bs[tid] = (j0 + tid < DF) ? bias[j0 + tid] : 0.f;
  int w = tid >> 6, lane = tid & 63, ln = lane & 15, lg = lane >> 4;
  int wm = (w >> 1)*32, wn = (w & 1)*32;
  const int NR = Bz*Mn;
  f32x4 acc[2][2];
  #pragma unroll
  for (int p = 0; p < 2; ++p)
    #pragma unroll
    for (int q = 0; q < 2; ++q) acc[p][q] = (f32x4)(0.f);

  for (int k0 = 0; k0 < 192; k0 += 64) {
    for (int idx = tid; idx < 2048; idx += 256) {
      int r = idx >> 5, cp = idx & 31;
      int i = i0 + r, k = k0 + 2*cp;
      unsigned int v = 0;
      if (i < NR && k < DF)
        v = *reinterpret_cast<const unsigned int*>(&tmpB[(size_t)i*DF + k]);
      *reinterpret_cast<unsigned int*>(&As[r*72 + 2*cp]) = v;
    }
    for (int idx = tid; idx < 2048; idx += 256) {
      int c = idx & 63, rp = idx >> 6;
      int j = j0 + c, k = k0 + 2*rp;
      unsigned int v = 0;
      if (j < DF && k < DF)
        v = pack2h(W[(size_t)k*DF + j], W[(size_t)(k+1)*DF + j]);
      *reinterpret_cast<unsigned int*>(&Bs[c*72 + 2*rp]) = v;
    }
    __syncthreads();
    #pragma unroll
    for (int kk = 0; kk < 2; ++kk) {
      half8 a0 = *reinterpret_cast<const half8*>(&As[(wm + 0  + ln)*72 + kk*32 + lg*8]);
      half8 a1 = *reinterpret_cast<const half8*>(&As[(wm + 16 + ln)*72 + kk*32 + lg*8]);
      half8 b0 = *reinterpret_cast<const half8*>(&Bs[(wn + 0  + ln)*72 + kk*32 + lg*8]);
      half8 b1 = *reinterpret_cast<const half8*>(&Bs[(wn + 16 + ln)*72 + kk*32 + lg*8]);
      acc[0][0] = MFMAH(a0, b0, acc[0][0], 0, 0, 0);
      acc[0][1] = MFMAH(a0, b1, acc[0][1], 0, 0, 0);
      acc[1][0] = MFMAH(a1, b0, acc[1][0], 0, 0, 0);
      acc[1][1] = MFMAH(a1, b1, acc[1][1], 0, 0, 0);
    }
    __syncthreads();
  }
  #pragma unroll
  for (int mt = 0; mt < 2; ++mt)
    #pragma unroll
    for (int nt = 0; nt < 2; ++nt)
      #pragma unroll
      for (int r = 0; r < 4; ++r) {
        int i = i0 + wm + mt*16 + lg*4 + r;
        int jl = wn + nt*16 + ln;
        int j = j0 + jl;
        if (i < NR && j < DF) {
          float val = eluf(acc[mt][nt][r] + bs[jl]);
          fout[(size_t)i*DF + j] = val;
          if (foutT) {
            int bb = i / Mn, mm = i - bb*Mn;
            foutT[((size_t)bb*DF + j)*Mn + mm] = f2h(val);
          }
        }
      }
}

// ---------------------------------------------------------------------------
// K14: output projection
__global__ __launch_bounds__(256) void k_out(
    const float* __restrict__ f0, const float* __restrict__ f1, const float* __restrict__ f2,
    const float* __restrict__ lh, const in_t* __restrict__ ow, const in_t* __restrict__ ob,
    float* __restrict__ outp)
{
  __shared__ float w[FINALC];
  int tid = threadIdx.x;
  for (int i = tid; i < FINALC; i += 256) w[i] = ow[i];
  __syncthreads();
  int gid = blockIdx.x*256 + tid;
  if (gid >= Bz*Mn) return;
  float s = ob[0];
  const float* p0 = f0 + (size_t)gid*DF;
  const float* p1 = f1 + (size_t)gid*DF;
  const float* p2 = f2 + (size_t)gid*DF;
  const float* pl = lh + (size_t)gid*NHID;
  for (int c = 0; c < DF; ++c) s += p0[c]*w[c];
  for (int c = 0; c < DF; ++c) s += p1[c]*w[DF + c];
  for (int c = 0; c < DF; ++c) s += p2[c]*w[2*DF + c];
  for (int c = 0; c < NHID; ++c) s += pl[c]*w[3*DF + c];
  outp[gid] = s;
}

// ---------------------------------------------------------------------------
extern "C" void kernel_launch(void* const* d_in, const int* in_sizes, int n_in,
                              void* d_out, int out_size, void* d_ws, size_t ws_size,
                              hipStream_t stream)
{
  const in_t* x       = (const in_t*)d_in[0];
  const in_t* adj_geo = (const in_t*)d_in[1];
  const in_t* degree  = (const in_t*)d_in[2];
  const in_t* conv_s_w= (const in_t*)d_in[3];
  const in_t* conv_s_b= (const in_t*)d_in[4];
  const in_t* conv_l_w= (const in_t*)d_in[5];
  const in_t* conv_l_b= (const in_t*)d_in[6];
  const in_t* WQ_w    = (const in_t*)d_in[7];
  const in_t* WQ_b    = (const in_t*)d_in[8];
  const in_t* WK_w    = (const in_t*)d_in[9];
  const in_t* WK_b    = (const in_t*)d_in[10];
  const in_t* tenc_w  = (const in_t*)d_in[11];
  const in_t* tenc_b  = (const in_t*)d_in[12];
  const in_t* senc_w  = (const in_t*)d_in[13];
  const in_t* senc_b  = (const in_t*)d_in[14];
  const in_t* gru_Wih = (const in_t*)d_in[15];
  const in_t* gru_Whh = (const in_t*)d_in[16];
  const in_t* gru_bih = (const in_t*)d_in[17];
  const in_t* gru_bhh = (const in_t*)d_in[18];
  const in_t* Vv      = (const in_t*)d_in[19];
  const in_t* W1      = (const in_t*)d_in[20];
  const in_t* W2      = (const in_t*)d_in[21];
  const in_t* Wb      = (const in_t*)d_in[22];
  const in_t* bv      = (const in_t*)d_in[23];
  const in_t* b1      = (const in_t*)d_in[24];
  const in_t* wb      = (const in_t*)d_in[25];
  const in_t* d_gate  = (const in_t*)d_in[26];
  const in_t* gnn_w   = (const in_t*)d_in[27];
  const in_t* gnn_b   = (const in_t*)d_in[28];
  const in_t* out_w   = (const in_t*)d_in[29];
  const in_t* out_b   = (const in_t*)d_in[30];
  float* out = (float*)d_out;

  // workspace carve-up (float offsets)
  float* ws   = (float*)d_ws;
  float* hSC  = ws;                    // 128000
  float* Qb   = ws + 128000;           // 256000
  float* Ktb  = ws + 384000;           // 256000
  float* lh   = ws + 673280;           // 128000
  float* A1   = ws + 801280;           // 128000
  float* A2   = ws + 929280;           // 128000
  float* aB   = ws + 1057280;          // 2000000 (dead after k_cgemm; lapB overlays)
  float* cinv = ws + 3057280;          // 4000
  float* adjb = ws + 3061280;          // 2000000
  float* dmat = ws + 5061280;          // 250000
  float* f0   = ws + 5311280;          // 640000
  float* f1   = ws + 5951280;          // 640000
  float* f2   = ws + 6591280;          // 640000
  unsigned short* f0T  = (unsigned short*)(ws + 7231280);  // 640000 fp16
  unsigned short* tmpB = (unsigned short*)(ws + 7551280);  // 640000 fp16
  unsigned short* f1T  = (unsigned short*)(ws + 7871280);  // 640000 fp16
  unsigned short* lapB = (unsigned short*)aB;              // fp16 overlay (aB dead after cgemm)
  // transient partials in adjb region (adjb written only later by k_cgemm):
  float* Gpart = adjb;                 // 8*8*4096 = 262144
  float* Kpart = adjb + 262144;        // 8*8*64   = 4096
  float* ssp   = adjb + 266240;        // 8*8*500  = 32000

  k_conv<<<dim3(4, Bz), 128, 0, stream>>>(x, conv_s_w, conv_s_b, conv_l_w, conv_l_b, hSC, f0, f0T);
  k_qk<<<dim3(16), 256, 0, stream>>>(hSC, WQ_w, WQ_b, WK_w, WK_b, Qb, Ktb);
  k_gram<<<dim3(GSPLIT, Bz), 256, 0, stream>>>(Ktb, Gpart, Kpart);
  k_sglob<<<dim3(2, Bz), 256, 0, stream>>>(Qb, Gpart, Kpart, degree, tenc_w, tenc_b, senc_w, senc_b, f0, f0T);
  k_gru<<<dim3(500), 256, 0, stream>>>(x, gru_Wih, gru_Whh, gru_bih, gru_bhh, lh);
  k_a1a2<<<dim3(16), 256, 0, stream>>>(lh, W1, W2, A1, A2);
  k_dmat<<<dim3((Mn*Mn + 255)/256), 256, 0, stream>>>(d_gate, degree, dmat);
  k_pair<<<dim3(32, 32, Bz), 256, 0, stream>>>(A1, A2, Vv, b1, bv, aB);
  k_cnorm<<<dim3(4, 8, Bz), 128, 0, stream>>>(aB, ssp);
  k_cfin<<<dim3(16), 256, 0, stream>>>(ssp, cinv);
  k_cgemm<<<dim3(8, 8, Bz), 256, 0, stream>>>(aB, cinv, Wb, wb, adj_geo, dmat, adjb);
  k_lap<<<dim3(Mn, Bz), 256, 0, stream>>>(adjb, lapB);
  // GNN layer 0
  k_spmm<<<dim3(3, 8, Bz), 256, 0, stream>>>(lapB, f0T, tmpB);
  k_dense<<<dim3(3, 63), 256, 0, stream>>>(tmpB, gnn_w, gnn_b, f1, f1T);
  // GNN layer 1
  k_spmm<<<dim3(3, 8, Bz), 256, 0, stream>>>(lapB, f1T, tmpB);
  k_dense<<<dim3(3, 63), 256, 0, stream>>>(tmpB, gnn_w + DF*DF, gnn_b + DF, f2, (unsigned short*)nullptr);
  k_out<<<dim3(16), 256, 0, stream>>>(f0, f1, f2, lh, out_w, out_b, out);
}